// Round 4
// baseline (442.327 us; speedup 1.0000x reference)
//
#include <hip/hip_runtime.h>
#include <math.h>

#define N_NODES   100000
#define N_FEAT    512
#define HIDDEN    16
#define N_CLASSES 7
#define N_EDGES   3200000

// bucket = dst >> 7  (128 nodes per bucket)
#define BSHIFT 7
#define BNODES 128
#define BMASK  127
#define NBUK   782            // ceil(100000/128)
#define CHUNK  16384
#define NCHUNK 196            // ceil(3200000/16384)
#define CAP    6144           // LDS stage cap per bucket (mean 4092, sigma~64)

typedef short v8s __attribute__((ext_vector_type(8)));
typedef float v4f __attribute__((ext_vector_type(4)));

__device__ __forceinline__ float bf_lo(unsigned int p) { return __uint_as_float(p << 16); }
__device__ __forceinline__ float bf_hi(unsigned int p) { return __uint_as_float(p & 0xffff0000u); }
__device__ __forceinline__ unsigned int pack_bf2(float a, float b) {
    unsigned int ua = __float_as_uint(a); ua += 0x7fffu + ((ua >> 16) & 1u);
    unsigned int ub = __float_as_uint(b); ub += 0x7fffu + ((ub >> 16) & 1u);
    return (ua >> 16) | (ub & 0xffff0000u);
}

// ---------- pass 0: pre-pack W1 into MFMA B-fragments (once, 16 KB) ----------

__global__ __launch_bounds__(256) void k_wpack(const float* __restrict__ W1,
                                               unsigned int* __restrict__ wfrag_g) {
    int tid = threadIdx.x;
    int q0 = tid * 4;
#pragma unroll
    for (int qq = 0; qq < 4; qq++) {
        int q = q0 + qq;
        int s = q >> 6, l = q & 63;
        int n = l & 15, kb = s * 32 + (l >> 4) * 8;
        unsigned int* wp = &wfrag_g[q * 4];
#pragma unroll
        for (int h = 0; h < 4; h++)
            wp[h] = pack_bf2(W1[(kb + 2 * h) * 16 + n],
                             W1[(kb + 2 * h + 1) * 16 + n]);
    }
}

// ---------- pass 1: per-chunk bucket histograms ----------

__global__ __launch_bounds__(1024) void k_hist(const int* __restrict__ dst,
                                               int* __restrict__ hglob) {
    __shared__ int h[NBUK];
    int tid = threadIdx.x;
    for (int i = tid; i < NBUK; i += 1024) h[i] = 0;
    __syncthreads();
    int base = blockIdx.x * CHUNK;
    for (int i = tid; i < CHUNK; i += 1024) {
        int e = base + i;
        if (e < N_EDGES) atomicAdd(&h[dst[e] >> BSHIFT], 1);
    }
    __syncthreads();
    for (int i = tid; i < NBUK; i += 1024)
        hglob[blockIdx.x * NBUK + i] = h[i];
}

// ---------- pass 2: column sums -> btot, exclusive scan -> gbase, chunk-prefixed bases -> hpre ----------

__global__ __launch_bounds__(1024) void k_scan(const int* __restrict__ hglob,
                                               int* __restrict__ btot,
                                               int* __restrict__ gbase,
                                               int* __restrict__ hpre) {
    __shared__ int sd[1024];
    int t = threadIdx.x;
    int tot = 0;
    if (t < NBUK)
        for (int c = 0; c < NCHUNK; c++) tot += hglob[c * NBUK + t];
    sd[t] = (t < NBUK) ? tot : 0;
    __syncthreads();
    for (int off = 1; off < 1024; off <<= 1) {
        int a = (t >= off) ? sd[t - off] : 0;
        __syncthreads();
        sd[t] += a;
        __syncthreads();
    }
    if (t < NBUK) {
        int ex = sd[t] - tot;  // exclusive
        btot[t] = tot;
        gbase[t] = ex;
        int run = ex;
        for (int c = 0; c < NCHUNK; c++) {
            hpre[c * NBUK + t] = run;
            run += hglob[c * NBUK + t];
        }
    }
}

// ---------- pass 3: scatter via in-LDS per-chunk counting sort -> coalesced global writes ----------

__global__ __launch_bounds__(1024) void k_scatter(const int* __restrict__ src,
                                                  const int* __restrict__ dst,
                                                  const int* __restrict__ hpre,
                                                  int* __restrict__ entries) {
    __shared__ int lb[NBUK];               // global base of this chunk's run per bucket
    __shared__ int cur[NBUK];              // per-bucket count within chunk
    __shared__ int lbase[NBUK];            // local exclusive prefix
    __shared__ int sd[1024];
    __shared__ int sbuf[CHUNK];            // 64 KB sorted entries
    __shared__ unsigned short sbk[CHUNK];  // 32 KB bucket id per sorted slot
    int tid = threadIdx.x;
    int base = blockIdx.x * CHUNK;

    for (int i = tid; i < NBUK; i += 1024) {
        lb[i] = hpre[blockIdx.x * NBUK + i];
        cur[i] = 0;
    }
    __syncthreads();

    int myent[16];
    int mypos[16];  // (b<<14)|r, or -1 for invalid
#pragma unroll
    for (int u = 0; u < 16; u++) {
        int e = base + u * 1024 + tid;  // coalesced
        int en = 0, bp = -1;
        if (e < N_EDGES) {
            int d = dst[e];
            int b = d >> BSHIFT;
            int r = atomicAdd(&cur[b], 1);           // rank within chunk-run
            en = src[e] | ((d & BMASK) << 17);       // src<2^17, loc 7 bits
            bp = (b << 14) | r;                      // r < 16384
        }
        myent[u] = en;
        mypos[u] = bp;
    }
    __syncthreads();

    // block-wide exclusive scan of cur -> lbase
    int v = (tid < NBUK) ? cur[tid] : 0;
    sd[tid] = v;
    __syncthreads();
    for (int off = 1; off < 1024; off <<= 1) {
        int a = (tid >= off) ? sd[tid - off] : 0;
        __syncthreads();
        sd[tid] += a;
        __syncthreads();
    }
    if (tid < NBUK) lbase[tid] = sd[tid] - v;
    __syncthreads();

    // scatter into LDS (random banks, cheap)
#pragma unroll
    for (int u = 0; u < 16; u++) {
        int bp = mypos[u];
        if (bp >= 0) {
            int b = bp >> 14, r = bp & 0x3FFF;
            int p = lbase[b] + r;
            sbuf[p] = myent[u];
            sbk[p] = (unsigned short)b;
        }
    }
    __syncthreads();

    // contiguous-run copy out
    int lim = N_EDGES - base;
    if (lim > CHUNK) lim = CHUNK;
    for (int i = tid; i < lim; i += 1024) {
        int b = sbk[i];
        entries[lb[b] + (i - lbase[b])] = sbuf[i];
    }
}

// ---------- pass 4: per-bucket degree histogram -> dinv (needed before gemm1) ----------

__global__ __launch_bounds__(256) void k_deg(const int* __restrict__ entries,
                                             const int* __restrict__ btot,
                                             const int* __restrict__ gbase,
                                             float* __restrict__ dinv) {
    __shared__ int hcnt[BNODES];
    int tid = threadIdx.x;
    int bk = blockIdx.x;
    if (tid < BNODES) hcnt[tid] = 0;
    __syncthreads();
    int cnt = btot[bk], base = gbase[bk];
    for (int i = tid; i < cnt; i += 256)
        atomicAdd(&hcnt[entries[base + i] >> 17], 1);
    __syncthreads();
    if (tid < BNODES) {
        int n = bk * BNODES + tid;
        if (n < N_NODES) dinv[n] = rsqrtf((float)(hcnt[tid] + 1));  // +1 self-loop
    }
}

// ---------- GEMM1 via MFMA: hs1 = bf16( dinv ⊙ (x @ W1) ) ----------
// Direct per-lane A loads (no A staging, no K-loop barriers); W prepacked in wfrag_g.
// LDS 20.4 KB -> 7 blocks/CU.

__global__ __launch_bounds__(256) void k_gemm1(const float* __restrict__ x,
                                               const unsigned int* __restrict__ wfrag_g,
                                               const float* __restrict__ dinv,
                                               unsigned int* __restrict__ hs1b) {
    __shared__ unsigned int wfrag[16 * 64 * 4];  // 16 KB
    __shared__ float dtile[4 * 16 * 17];         // 4.4 KB epilogue staging

    int tid = threadIdx.x;
    int wave = tid >> 6, lane = tid & 63;
    int row0 = blockIdx.x * 64;
    int m = lane & 15, quad = lane >> 4;

    // coalesced copy of prepacked W fragments (L2-hot after k_wpack)
    {
        const uint4* wg = (const uint4*)wfrag_g;
        uint4* wl = (uint4*)wfrag;
        for (int i = tid; i < 1024; i += 256) wl[i] = wg[i];
    }

    int grow = row0 + wave * 16 + m;
    bool vrow = (grow < N_NODES);
    const float* xr = x + (size_t)(vrow ? grow : 0) * N_FEAT + quad * 8;

    v4f acc = {0.f, 0.f, 0.f, 0.f};
    __syncthreads();

#pragma unroll
    for (int c = 0; c < 16; c++) {
        float4 xa = make_float4(0.f, 0.f, 0.f, 0.f);
        float4 xb = make_float4(0.f, 0.f, 0.f, 0.f);
        if (vrow) {
            xa = *(const float4*)(xr + c * 32);
            xb = *(const float4*)(xr + c * 32 + 4);
        }
        unsigned int pa[4] = {pack_bf2(xa.x, xa.y), pack_bf2(xa.z, xa.w),
                              pack_bf2(xb.x, xb.y), pack_bf2(xb.z, xb.w)};
        v8s af;
        __builtin_memcpy(&af, pa, 16);
        v8s bf = *(const v8s*)&wfrag[(c * 64 + lane) * 4];
        acc = __builtin_amdgcn_mfma_f32_16x16x32_bf16(af, bf, acc, 0, 0, 0);
    }

    // epilogue: D[row=quad*4+r][col=lane&15] -> LDS -> packed bf16x2 coalesced store
    {
        float* wdt = dtile + wave * 272;  // 16*17 floats per wave
#pragma unroll
        for (int r = 0; r < 4; r++)
            wdt[(quad * 4 + r) * 17 + m] = acc[r];
    }
    __syncthreads();
    {
        int row = tid >> 2, p = tid & 3;
        int orow = row0 + row;
        if (orow < N_NODES) {
            float dn = dinv[orow];
            float* wdt = dtile + (row >> 4) * 272 + (row & 15) * 17 + 4 * p;
            unsigned int d0 = pack_bf2(dn * wdt[0], dn * wdt[1]);
            unsigned int d1 = pack_bf2(dn * wdt[2], dn * wdt[3]);
            *(uint2*)(hs1b + (size_t)orow * 8 + 2 * p) = make_uint2(d0, d1);
        }
    }
}

// ---------- layer1 aggregate: fused in-LDS node sort + register aggregation ----------
// Prologue = old nodesort (writes sorted srcs for agg2 + nodeptr); aggregation uses
// run bounds from LDS hincl/hcnt and reads the just-written (L2-hot) sorted srcs.

__global__ __launch_bounds__(512) void k_agg1(const unsigned int* __restrict__ hs1b,
                                              int* __restrict__ entries,
                                              const int* __restrict__ btot,
                                              const int* __restrict__ gbase,
                                              const float* __restrict__ dinv,
                                              const float* __restrict__ b1,
                                              const float* __restrict__ W2,
                                              unsigned int* __restrict__ hs2b,
                                              int* __restrict__ nodeptr) {
    __shared__ int ebuf[CAP];
    __shared__ int hcnt[BNODES];
    __shared__ int hincl[BNODES];
    __shared__ int hcur[BNODES];
    __shared__ float w2l[HIDDEN * N_CLASSES];
    __shared__ float b1l[HIDDEN];
    __shared__ float part[BNODES][17];
    int tid = threadIdx.x;
    int bk = blockIdx.x;
    if (tid < HIDDEN * N_CLASSES) w2l[tid] = W2[tid];
    if (tid < HIDDEN) b1l[tid] = b1[tid];
    if (tid < BNODES) hcnt[tid] = 0;
    int cnt = btot[bk], base = gbase[bk];
    if (cnt > CAP) cnt = CAP;  // statistically impossible; guards LDS
    __syncthreads();

    for (int i = tid; i < cnt; i += 512) {
        int en = entries[base + i];
        ebuf[i] = en;
        atomicAdd(&hcnt[en >> 17], 1);
    }
    __syncthreads();
    if (tid < BNODES) hincl[tid] = hcnt[tid];
    __syncthreads();
    for (int off = 1; off < BNODES; off <<= 1) {
        int v = 0;
        if (tid < BNODES && tid >= off) v = hincl[tid - off];
        __syncthreads();
        if (tid < BNODES) hincl[tid] += v;
        __syncthreads();
    }
    if (tid < BNODES) {
        int excl = hincl[tid] - hcnt[tid];
        hcur[tid] = excl;
        int n = bk * BNODES + tid;
        if (n <= N_NODES) nodeptr[n] = base + excl;  // incl. sentinel at n==N_NODES
    }
    __syncthreads();
    for (int i = tid; i < cnt; i += 512) {
        int en = ebuf[i];
        int pos = atomicAdd(&hcur[en >> 17], 1);
        entries[base + pos] = en & 0x1FFFF;  // plain src id (for agg2 + our gather below)
    }
    __syncthreads();

    // aggregation: 512 thr = 256 pairs = 128 nodes x 2 halves; lane j owns channels 8j..8j+7
    int g = tid >> 1, j = tid & 1;
    int l = g & (BNODES - 1), half = g >> 7;
    int n = bk * BNODES + l;
    bool valid = (n < N_NODES);

    float accL[4] = {0.f, 0.f, 0.f, 0.f};
    float accH[4] = {0.f, 0.f, 0.f, 0.f};
    const uint4* hv = (const uint4*)hs1b;  // 2 uint4 per node
    const int* srt = entries;

    if (valid) {
        int p0 = base + hincl[l] - hcnt[l];
        int p1 = base + hincl[l];
        int mid = p0 + ((p1 - p0) >> 1);
        int e0 = half ? mid : p0;
        int e1 = half ? p1 : mid;
        int e = e0;
        for (; e + 4 <= e1; e += 4) {
            int s[4];
            uint4 v[4];
#pragma unroll
            for (int u = 0; u < 4; u++) s[u] = srt[e + u];
#pragma unroll
            for (int u = 0; u < 4; u++) v[u] = hv[(size_t)s[u] * 2 + j];
#pragma unroll
            for (int u = 0; u < 4; u++) {
                accL[0] += bf_lo(v[u].x); accH[0] += bf_hi(v[u].x);
                accL[1] += bf_lo(v[u].y); accH[1] += bf_hi(v[u].y);
                accL[2] += bf_lo(v[u].z); accH[2] += bf_hi(v[u].z);
                accL[3] += bf_lo(v[u].w); accH[3] += bf_hi(v[u].w);
            }
        }
        for (; e < e1; e++) {
            uint4 v0 = hv[(size_t)srt[e] * 2 + j];
            accL[0] += bf_lo(v0.x); accH[0] += bf_hi(v0.x);
            accL[1] += bf_lo(v0.y); accH[1] += bf_hi(v0.y);
            accL[2] += bf_lo(v0.z); accH[2] += bf_hi(v0.z);
            accL[3] += bf_lo(v0.w); accH[3] += bf_hi(v0.w);
        }
        if (half == 0) {  // self-loop added once per (n,j)
            uint4 sv = hv[(size_t)n * 2 + j];
            accL[0] += bf_lo(sv.x); accH[0] += bf_hi(sv.x);
            accL[1] += bf_lo(sv.y); accH[1] += bf_hi(sv.y);
            accL[2] += bf_lo(sv.z); accH[2] += bf_hi(sv.z);
            accL[3] += bf_lo(sv.w); accH[3] += bf_hi(sv.w);
        }
    }

    if (half == 1 && valid) {
#pragma unroll
        for (int q = 0; q < 4; q++) {
            int ch = j * 8 + 2 * q;
            part[l][ch]     = accL[q];
            part[l][ch + 1] = accH[q];
        }
    }
    __syncthreads();

    if (half == 0 && valid) {
        float dn = dinv[n];
        float t[7] = {0.f, 0.f, 0.f, 0.f, 0.f, 0.f, 0.f};
#pragma unroll
        for (int q = 0; q < 4; q++) {
            int ch = j * 8 + 2 * q;
            float z0 = fmaxf(dn * (accL[q] + part[l][ch])     + b1l[ch],     0.f);
            float z1 = fmaxf(dn * (accH[q] + part[l][ch + 1]) + b1l[ch + 1], 0.f);
            const float* w0 = &w2l[ch * 7];
            const float* w1 = &w2l[(ch + 1) * 7];
#pragma unroll
            for (int k = 0; k < 7; k++) t[k] += z0 * w0[k] + z1 * w1[k];
        }
#pragma unroll
        for (int k = 0; k < 7; k++) t[k] += __shfl_xor(t[k], 1, 64);
        if (j == 0) {
            uint4 o;
            o.x = pack_bf2(dn * t[0], dn * t[1]);
            o.y = pack_bf2(dn * t[2], dn * t[3]);
            o.z = pack_bf2(dn * t[4], dn * t[5]);
            o.w = pack_bf2(dn * t[6], 0.f);
            ((uint4*)hs2b)[n] = o;
        }
    }
}

// ---------- layer2 aggregate: 4-lane quarter-split, whole-vector uint4 gathers ----------

__global__ __launch_bounds__(512) void k_agg2(const unsigned int* __restrict__ hs2b,
                                              const int* __restrict__ srt,
                                              const int* __restrict__ nodeptr,
                                              const float* __restrict__ dinv,
                                              const float* __restrict__ b2,
                                              float* __restrict__ out) {
    int tid = threadIdx.x;
    int bk = blockIdx.x;
    int l = tid >> 2, h = tid & 3;
    int n = bk * BNODES + l;
    bool valid = (n < N_NODES);

    float a[8] = {0.f, 0.f, 0.f, 0.f, 0.f, 0.f, 0.f, 0.f};
    const uint4* hv = (const uint4*)hs2b;  // 1 uint4 per node

    if (valid) {
        int p0 = nodeptr[n], p1 = nodeptr[n + 1];
        int deg = p1 - p0;
        int e0 = p0 + ((deg * h) >> 2);
        int e1 = p0 + ((deg * (h + 1)) >> 2);
        int e = e0;
        for (; e + 4 <= e1; e += 4) {
            int s[4];
            uint4 v[4];
#pragma unroll
            for (int u = 0; u < 4; u++) s[u] = srt[e + u];
#pragma unroll
            for (int u = 0; u < 4; u++) v[u] = hv[s[u]];
#pragma unroll
            for (int u = 0; u < 4; u++) {
                a[0] += bf_lo(v[u].x); a[1] += bf_hi(v[u].x);
                a[2] += bf_lo(v[u].y); a[3] += bf_hi(v[u].y);
                a[4] += bf_lo(v[u].z); a[5] += bf_hi(v[u].z);
                a[6] += bf_lo(v[u].w);
            }
        }
        for (; e < e1; e++) {
            uint4 v0 = hv[srt[e]];
            a[0] += bf_lo(v0.x); a[1] += bf_hi(v0.x);
            a[2] += bf_lo(v0.y); a[3] += bf_hi(v0.y);
            a[4] += bf_lo(v0.z); a[5] += bf_hi(v0.z);
            a[6] += bf_lo(v0.w);
        }
        if (h == 0) {  // self-loop once
            uint4 sv = hv[n];
            a[0] += bf_lo(sv.x); a[1] += bf_hi(sv.x);
            a[2] += bf_lo(sv.y); a[3] += bf_hi(sv.y);
            a[4] += bf_lo(sv.z); a[5] += bf_hi(sv.z);
            a[6] += bf_lo(sv.w);
        }
#pragma unroll
        for (int q = 0; q < 7; q++) {
            a[q] += __shfl_xor(a[q], 1, 64);
            a[q] += __shfl_xor(a[q], 2, 64);
        }
        if (h == 0) {
            float dn = dinv[n];
            float lg[7];
#pragma unroll
            for (int c = 0; c < 7; c++) lg[c] = dn * a[c] + b2[c];
            float m = lg[0];
#pragma unroll
            for (int c = 1; c < 7; c++) m = fmaxf(m, lg[c]);
            float s = 0.f;
#pragma unroll
            for (int c = 0; c < 7; c++) s += expf(lg[c] - m);
            float ls = m + logf(s);
#pragma unroll
            for (int c = 0; c < 7; c++) out[(size_t)n * 7 + c] = lg[c] - ls;
        }
    }
}

// ---------- launch ----------

extern "C" void kernel_launch(void* const* d_in, const int* in_sizes, int n_in,
                              void* d_out, int out_size, void* d_ws, size_t ws_size,
                              hipStream_t stream) {
    const float* x  = (const float*)d_in[0];
    const int*   ei = (const int*)d_in[1];
    const float* W1 = (const float*)d_in[2];
    const float* b1 = (const float*)d_in[3];
    const float* W2 = (const float*)d_in[4];
    const float* b2 = (const float*)d_in[5];
    float* out = (float*)d_out;

    const int* src = ei;
    const int* dst = ei + N_EDGES;

    char* w = (char*)d_ws;
    int*          btot    = (int*)(w + 0);          //   3128 B
    int*          gbase   = (int*)(w + 4096);       //   3128 B
    float*        dinv    = (float*)(w + 8192);     // 400000 B
    int*          nodeptr = (int*)(w + 408576);     // 400004 B (incl. sentinel)
    int*          hglob   = (int*)(w + 808960);     // 613088 B
    int*          hpre    = (int*)(w + 1422336);    // 613088 B
    unsigned int* hs1b    = (unsigned int*)(w + 2036736);  // 3.2 MB (bf16x2)
    unsigned int* hs2b    = (unsigned int*)(w + 5236736);  // 1.6 MB (bf16x2)
    int*          entries = (int*)(w + 6836736);    // 12.8 MB
    unsigned int* wfrag_g = (unsigned int*)(w + 19636736); // 16 KB prepacked W1

    k_wpack   <<<1, 256, 0, stream>>>(W1, wfrag_g);
    k_hist    <<<NCHUNK, 1024, 0, stream>>>(dst, hglob);
    k_scan    <<<1, 1024, 0, stream>>>(hglob, btot, gbase, hpre);
    k_scatter <<<NCHUNK, 1024, 0, stream>>>(src, dst, hpre, entries);
    k_deg     <<<NBUK, 256, 0, stream>>>(entries, btot, gbase, dinv);
    k_gemm1   <<<1563, 256, 0, stream>>>(x, wfrag_g, dinv, hs1b);
    k_agg1    <<<NBUK, 512, 0, stream>>>(hs1b, entries, btot, gbase, dinv, b1, W2, hs2b, nodeptr);
    k_agg2    <<<NBUK, 512, 0, stream>>>(hs2b, entries, nodeptr, dinv, b2, out);
}

// Round 5
// 423.635 us; speedup vs baseline: 1.0441x; 1.0441x over previous
//
#include <hip/hip_runtime.h>
#include <math.h>

#define N_NODES   100000
#define N_FEAT    512
#define HIDDEN    16
#define N_CLASSES 7
#define N_EDGES   3200000

// bucket = dst >> 7  (128 nodes per bucket)
#define BSHIFT 7
#define BNODES 128
#define BMASK  127
#define NBUK   782            // ceil(100000/128)
#define CHUNK  16384
#define NCHUNK 196            // ceil(3200000/16384)
#define CAP    6144           // LDS stage cap per bucket (mean 4092, sigma~64)

typedef short v8s __attribute__((ext_vector_type(8)));
typedef float v4f __attribute__((ext_vector_type(4)));

__device__ __forceinline__ float bf_lo(unsigned int p) { return __uint_as_float(p << 16); }
__device__ __forceinline__ float bf_hi(unsigned int p) { return __uint_as_float(p & 0xffff0000u); }
__device__ __forceinline__ unsigned int pack_bf2(float a, float b) {
    unsigned int ua = __float_as_uint(a); ua += 0x7fffu + ((ua >> 16) & 1u);
    unsigned int ub = __float_as_uint(b); ub += 0x7fffu + ((ub >> 16) & 1u);
    return (ua >> 16) | (ub & 0xffff0000u);
}

// wave64 inclusive scan (no barriers)
__device__ __forceinline__ int wincl(int v, int lane) {
#pragma unroll
    for (int off = 1; off < 64; off <<= 1) {
        int u = __shfl_up(v, off, 64);
        if (lane >= off) v += u;
    }
    return v;
}

// ---------- pass 1: per-chunk bucket histograms; block NCHUNK packs W1 fragments ----------

__global__ __launch_bounds__(1024) void k_hist(const int* __restrict__ dst,
                                               int* __restrict__ hglob,
                                               const float* __restrict__ W1,
                                               unsigned int* __restrict__ wfrag_g) {
    __shared__ int h[NBUK];
    int tid = threadIdx.x;
    if (blockIdx.x == NCHUNK) {  // W-pack block: q = tid covers all 16*64 slots
        int q = tid;
        int s = q >> 6, l = q & 63;
        int n = l & 15, kb = s * 32 + (l >> 4) * 8;
        unsigned int* wp = &wfrag_g[q * 4];
#pragma unroll
        for (int hh = 0; hh < 4; hh++)
            wp[hh] = pack_bf2(W1[(kb + 2 * hh) * 16 + n],
                              W1[(kb + 2 * hh + 1) * 16 + n]);
        return;
    }
    for (int i = tid; i < NBUK; i += 1024) h[i] = 0;
    __syncthreads();
    int base = blockIdx.x * CHUNK;
    for (int i = tid; i < CHUNK; i += 1024) {
        int e = base + i;
        if (e < N_EDGES) atomicAdd(&h[dst[e] >> BSHIFT], 1);
    }
    __syncthreads();
    for (int i = tid; i < NBUK; i += 1024)
        hglob[blockIdx.x * NBUK + i] = h[i];
}

// ---------- pass 2a: per-bucket chunk-prefix column scan -> hpre (LOCAL prefixes), btot ----------

__global__ __launch_bounds__(256) void k_hpre(const int* __restrict__ hglob,
                                              int* __restrict__ hpre,
                                              int* __restrict__ btot) {
    __shared__ int wsum[4];
    int b = blockIdx.x;
    int t = threadIdx.x;           // chunk index c
    int lane = t & 63, w = t >> 6;
    int v = (t < NCHUNK) ? hglob[t * NBUK + b] : 0;
    int inc = wincl(v, lane);
    if (lane == 63) wsum[w] = inc;
    __syncthreads();
    int off = 0;
#pragma unroll
    for (int k = 0; k < 4; k++) off += (k < w) ? wsum[k] : 0;
    int excl = off + inc - v;
    if (t < NCHUNK) hpre[t * NBUK + b] = excl;       // local (bucket-relative) prefix
    if (t == NCHUNK - 1) btot[b] = excl + v;         // bucket total
}

// ---------- pass 2b: tiny exclusive scan of bucket totals -> gbase ----------

__global__ __launch_bounds__(1024) void k_scan(const int* __restrict__ btot,
                                               int* __restrict__ gbase) {
    __shared__ int wsum[16];
    int t = threadIdx.x, lane = t & 63, w = t >> 6;
    int v = (t < NBUK) ? btot[t] : 0;
    int inc = wincl(v, lane);
    if (lane == 63) wsum[w] = inc;
    __syncthreads();
    int off = 0;
#pragma unroll
    for (int k = 0; k < 16; k++) off += (k < w) ? wsum[k] : 0;
    if (t < NBUK) gbase[t] = off + inc - v;
}

// ---------- pass 3: scatter via in-LDS per-chunk counting sort -> coalesced global writes ----------

__global__ __launch_bounds__(1024) void k_scatter(const int* __restrict__ src,
                                                  const int* __restrict__ dst,
                                                  const int* __restrict__ hpre,
                                                  const int* __restrict__ gbase,
                                                  int* __restrict__ entries) {
    __shared__ int lb[NBUK];               // global base of this chunk's run per bucket
    __shared__ int cur[NBUK];              // per-bucket count within chunk
    __shared__ int lbase[NBUK];            // local exclusive prefix
    __shared__ int wsum[16];
    __shared__ int sbuf[CHUNK];            // 64 KB sorted entries
    __shared__ unsigned short sbk[CHUNK];  // 32 KB bucket id per sorted slot
    int tid = threadIdx.x;
    int base = blockIdx.x * CHUNK;

    for (int i = tid; i < NBUK; i += 1024) {
        lb[i] = gbase[i] + hpre[blockIdx.x * NBUK + i];
        cur[i] = 0;
    }
    __syncthreads();

    int myent[16];
    int mypos[16];  // (b<<14)|r, or -1 for invalid
#pragma unroll
    for (int u = 0; u < 16; u++) {
        int e = base + u * 1024 + tid;  // coalesced
        int en = 0, bp = -1;
        if (e < N_EDGES) {
            int d = dst[e];
            int b = d >> BSHIFT;
            int r = atomicAdd(&cur[b], 1);           // rank within chunk-run
            en = src[e] | ((d & BMASK) << 17);       // src<2^17, loc 7 bits
            bp = (b << 14) | r;                      // r < 16384
        }
        myent[u] = en;
        mypos[u] = bp;
    }
    __syncthreads();

    // block-wide exclusive scan of cur -> lbase (wave-shfl based, 2 barriers)
    {
        int lane = tid & 63, w = tid >> 6;
        int v = (tid < NBUK) ? cur[tid] : 0;
        int inc = wincl(v, lane);
        if (lane == 63) wsum[w] = inc;
        __syncthreads();
        int off = 0;
#pragma unroll
        for (int k = 0; k < 16; k++) off += (k < w) ? wsum[k] : 0;
        if (tid < NBUK) lbase[tid] = off + inc - v;
        __syncthreads();
    }

    // scatter into LDS (random banks, cheap)
#pragma unroll
    for (int u = 0; u < 16; u++) {
        int bp = mypos[u];
        if (bp >= 0) {
            int b = bp >> 14, r = bp & 0x3FFF;
            int p = lbase[b] + r;
            sbuf[p] = myent[u];
            sbk[p] = (unsigned short)b;
        }
    }
    __syncthreads();

    // contiguous-run copy out
    int lim = N_EDGES - base;
    if (lim > CHUNK) lim = CHUNK;
    for (int i = tid; i < lim; i += 1024) {
        int b = sbk[i];
        entries[lb[b] + (i - lbase[b])] = sbuf[i];
    }
}

// ---------- pass 4: per-bucket degree histogram -> dinv (needed before gemm1) ----------

__global__ __launch_bounds__(256) void k_deg(const int* __restrict__ entries,
                                             const int* __restrict__ btot,
                                             const int* __restrict__ gbase,
                                             float* __restrict__ dinv) {
    __shared__ int hcnt[BNODES];
    int tid = threadIdx.x;
    int bk = blockIdx.x;
    if (tid < BNODES) hcnt[tid] = 0;
    __syncthreads();
    int cnt = btot[bk], base = gbase[bk];
    for (int i = tid; i < cnt; i += 256)
        atomicAdd(&hcnt[entries[base + i] >> 17], 1);
    __syncthreads();
    if (tid < BNODES) {
        int n = bk * BNODES + tid;
        if (n < N_NODES) dinv[n] = rsqrtf((float)(hcnt[tid] + 1));  // +1 self-loop
    }
}

// ---------- GEMM1 via MFMA: hs1 = bf16( dinv ⊙ (x @ W1) ) ----------
// Direct per-lane A loads (no A staging, no K-loop barriers); W prepacked in wfrag_g.

__global__ __launch_bounds__(256) void k_gemm1(const float* __restrict__ x,
                                               const unsigned int* __restrict__ wfrag_g,
                                               const float* __restrict__ dinv,
                                               unsigned int* __restrict__ hs1b) {
    __shared__ unsigned int wfrag[16 * 64 * 4];  // 16 KB
    __shared__ float dtile[4 * 16 * 17];         // 4.4 KB epilogue staging

    int tid = threadIdx.x;
    int wave = tid >> 6, lane = tid & 63;
    int row0 = blockIdx.x * 64;
    int m = lane & 15, quad = lane >> 4;

    // coalesced copy of prepacked W fragments (L2-hot after k_hist's wpack block)
    {
        const uint4* wg = (const uint4*)wfrag_g;
        uint4* wl = (uint4*)wfrag;
        for (int i = tid; i < 1024; i += 256) wl[i] = wg[i];
    }

    int grow = row0 + wave * 16 + m;
    bool vrow = (grow < N_NODES);
    const float* xr = x + (size_t)(vrow ? grow : 0) * N_FEAT + quad * 8;

    v4f acc = {0.f, 0.f, 0.f, 0.f};
    __syncthreads();

#pragma unroll
    for (int c = 0; c < 16; c++) {
        float4 xa = make_float4(0.f, 0.f, 0.f, 0.f);
        float4 xb = make_float4(0.f, 0.f, 0.f, 0.f);
        if (vrow) {
            xa = *(const float4*)(xr + c * 32);
            xb = *(const float4*)(xr + c * 32 + 4);
        }
        unsigned int pa[4] = {pack_bf2(xa.x, xa.y), pack_bf2(xa.z, xa.w),
                              pack_bf2(xb.x, xb.y), pack_bf2(xb.z, xb.w)};
        v8s af;
        __builtin_memcpy(&af, pa, 16);
        v8s bf = *(const v8s*)&wfrag[(c * 64 + lane) * 4];
        acc = __builtin_amdgcn_mfma_f32_16x16x32_bf16(af, bf, acc, 0, 0, 0);
    }

    // epilogue: D[row=quad*4+r][col=lane&15] -> LDS -> packed bf16x2 coalesced store
    {
        float* wdt = dtile + wave * 272;  // 16*17 floats per wave
#pragma unroll
        for (int r = 0; r < 4; r++)
            wdt[(quad * 4 + r) * 17 + m] = acc[r];
    }
    __syncthreads();
    {
        int row = tid >> 2, p = tid & 3;
        int orow = row0 + row;
        if (orow < N_NODES) {
            float dn = dinv[orow];
            float* wdt = dtile + (row >> 4) * 272 + (row & 15) * 17 + 4 * p;
            unsigned int d0 = pack_bf2(dn * wdt[0], dn * wdt[1]);
            unsigned int d1 = pack_bf2(dn * wdt[2], dn * wdt[3]);
            *(uint2*)(hs1b + (size_t)orow * 8 + 2 * p) = make_uint2(d0, d1);
        }
    }
}

// ---------- layer1 aggregate: fused in-LDS node sort + register aggregation ----------

__global__ __launch_bounds__(512) void k_agg1(const unsigned int* __restrict__ hs1b,
                                              int* __restrict__ entries,
                                              const int* __restrict__ btot,
                                              const int* __restrict__ gbase,
                                              const float* __restrict__ dinv,
                                              const float* __restrict__ b1,
                                              const float* __restrict__ W2,
                                              unsigned int* __restrict__ hs2b,
                                              int* __restrict__ nodeptr) {
    __shared__ int ebuf[CAP];
    __shared__ int hcnt[BNODES];
    __shared__ int hincl[BNODES];
    __shared__ int hcur[BNODES];
    __shared__ float w2l[HIDDEN * N_CLASSES];
    __shared__ float b1l[HIDDEN];
    __shared__ float part[BNODES][17];
    int tid = threadIdx.x;
    int bk = blockIdx.x;
    if (tid < HIDDEN * N_CLASSES) w2l[tid] = W2[tid];
    if (tid < HIDDEN) b1l[tid] = b1[tid];
    if (tid < BNODES) hcnt[tid] = 0;
    int cnt = btot[bk], base = gbase[bk];
    if (cnt > CAP) cnt = CAP;  // statistically impossible; guards LDS
    __syncthreads();

    for (int i = tid; i < cnt; i += 512) {
        int en = entries[base + i];
        ebuf[i] = en;
        atomicAdd(&hcnt[en >> 17], 1);
    }
    __syncthreads();
    if (tid < BNODES) hincl[tid] = hcnt[tid];
    __syncthreads();
    for (int off = 1; off < BNODES; off <<= 1) {
        int v = 0;
        if (tid < BNODES && tid >= off) v = hincl[tid - off];
        __syncthreads();
        if (tid < BNODES) hincl[tid] += v;
        __syncthreads();
    }
    if (tid < BNODES) {
        int excl = hincl[tid] - hcnt[tid];
        hcur[tid] = excl;
        int n = bk * BNODES + tid;
        if (n <= N_NODES) nodeptr[n] = base + excl;  // incl. sentinel at n==N_NODES
    }
    __syncthreads();
    for (int i = tid; i < cnt; i += 512) {
        int en = ebuf[i];
        int pos = atomicAdd(&hcur[en >> 17], 1);
        entries[base + pos] = en & 0x1FFFF;  // plain src id (for agg2 + our gather below)
    }
    __syncthreads();

    // aggregation: 512 thr = 256 pairs = 128 nodes x 2 halves; lane j owns channels 8j..8j+7
    int g = tid >> 1, j = tid & 1;
    int l = g & (BNODES - 1), half = g >> 7;
    int n = bk * BNODES + l;
    bool valid = (n < N_NODES);

    float accL[4] = {0.f, 0.f, 0.f, 0.f};
    float accH[4] = {0.f, 0.f, 0.f, 0.f};
    const uint4* hv = (const uint4*)hs1b;  // 2 uint4 per node
    const int* srt = entries;

    if (valid) {
        int p0 = base + hincl[l] - hcnt[l];
        int p1 = base + hincl[l];
        int mid = p0 + ((p1 - p0) >> 1);
        int e0 = half ? mid : p0;
        int e1 = half ? p1 : mid;
        int e = e0;
        for (; e + 4 <= e1; e += 4) {
            int s[4];
            uint4 v[4];
#pragma unroll
            for (int u = 0; u < 4; u++) s[u] = srt[e + u];
#pragma unroll
            for (int u = 0; u < 4; u++) v[u] = hv[(size_t)s[u] * 2 + j];
#pragma unroll
            for (int u = 0; u < 4; u++) {
                accL[0] += bf_lo(v[u].x); accH[0] += bf_hi(v[u].x);
                accL[1] += bf_lo(v[u].y); accH[1] += bf_hi(v[u].y);
                accL[2] += bf_lo(v[u].z); accH[2] += bf_hi(v[u].z);
                accL[3] += bf_lo(v[u].w); accH[3] += bf_hi(v[u].w);
            }
        }
        for (; e < e1; e++) {
            uint4 v0 = hv[(size_t)srt[e] * 2 + j];
            accL[0] += bf_lo(v0.x); accH[0] += bf_hi(v0.x);
            accL[1] += bf_lo(v0.y); accH[1] += bf_hi(v0.y);
            accL[2] += bf_lo(v0.z); accH[2] += bf_hi(v0.z);
            accL[3] += bf_lo(v0.w); accH[3] += bf_hi(v0.w);
        }
        if (half == 0) {  // self-loop added once per (n,j)
            uint4 sv = hv[(size_t)n * 2 + j];
            accL[0] += bf_lo(sv.x); accH[0] += bf_hi(sv.x);
            accL[1] += bf_lo(sv.y); accH[1] += bf_hi(sv.y);
            accL[2] += bf_lo(sv.z); accH[2] += bf_hi(sv.z);
            accL[3] += bf_lo(sv.w); accH[3] += bf_hi(sv.w);
        }
    }

    if (half == 1 && valid) {
#pragma unroll
        for (int q = 0; q < 4; q++) {
            int ch = j * 8 + 2 * q;
            part[l][ch]     = accL[q];
            part[l][ch + 1] = accH[q];
        }
    }
    __syncthreads();

    if (half == 0 && valid) {
        float dn = dinv[n];
        float t[7] = {0.f, 0.f, 0.f, 0.f, 0.f, 0.f, 0.f};
#pragma unroll
        for (int q = 0; q < 4; q++) {
            int ch = j * 8 + 2 * q;
            float z0 = fmaxf(dn * (accL[q] + part[l][ch])     + b1l[ch],     0.f);
            float z1 = fmaxf(dn * (accH[q] + part[l][ch + 1]) + b1l[ch + 1], 0.f);
            const float* w0 = &w2l[ch * 7];
            const float* w1 = &w2l[(ch + 1) * 7];
#pragma unroll
            for (int k = 0; k < 7; k++) t[k] += z0 * w0[k] + z1 * w1[k];
        }
#pragma unroll
        for (int k = 0; k < 7; k++) t[k] += __shfl_xor(t[k], 1, 64);
        if (j == 0) {
            uint4 o;
            o.x = pack_bf2(dn * t[0], dn * t[1]);
            o.y = pack_bf2(dn * t[2], dn * t[3]);
            o.z = pack_bf2(dn * t[4], dn * t[5]);
            o.w = pack_bf2(dn * t[6], 0.f);
            ((uint4*)hs2b)[n] = o;
        }
    }
}

// ---------- layer2 aggregate: 4-lane quarter-split, whole-vector uint4 gathers ----------

__global__ __launch_bounds__(512) void k_agg2(const unsigned int* __restrict__ hs2b,
                                              const int* __restrict__ srt,
                                              const int* __restrict__ nodeptr,
                                              const float* __restrict__ dinv,
                                              const float* __restrict__ b2,
                                              float* __restrict__ out) {
    int tid = threadIdx.x;
    int bk = blockIdx.x;
    int l = tid >> 2, h = tid & 3;
    int n = bk * BNODES + l;
    bool valid = (n < N_NODES);

    float a[8] = {0.f, 0.f, 0.f, 0.f, 0.f, 0.f, 0.f, 0.f};
    const uint4* hv = (const uint4*)hs2b;  // 1 uint4 per node

    if (valid) {
        int p0 = nodeptr[n], p1 = nodeptr[n + 1];
        int deg = p1 - p0;
        int e0 = p0 + ((deg * h) >> 2);
        int e1 = p0 + ((deg * (h + 1)) >> 2);
        int e = e0;
        for (; e + 4 <= e1; e += 4) {
            int s[4];
            uint4 v[4];
#pragma unroll
            for (int u = 0; u < 4; u++) s[u] = srt[e + u];
#pragma unroll
            for (int u = 0; u < 4; u++) v[u] = hv[s[u]];
#pragma unroll
            for (int u = 0; u < 4; u++) {
                a[0] += bf_lo(v[u].x); a[1] += bf_hi(v[u].x);
                a[2] += bf_lo(v[u].y); a[3] += bf_hi(v[u].y);
                a[4] += bf_lo(v[u].z); a[5] += bf_hi(v[u].z);
                a[6] += bf_lo(v[u].w);
            }
        }
        for (; e < e1; e++) {
            uint4 v0 = hv[srt[e]];
            a[0] += bf_lo(v0.x); a[1] += bf_hi(v0.x);
            a[2] += bf_lo(v0.y); a[3] += bf_hi(v0.y);
            a[4] += bf_lo(v0.z); a[5] += bf_hi(v0.z);
            a[6] += bf_lo(v0.w);
        }
        if (h == 0) {  // self-loop once
            uint4 sv = hv[n];
            a[0] += bf_lo(sv.x); a[1] += bf_hi(sv.x);
            a[2] += bf_lo(sv.y); a[3] += bf_hi(sv.y);
            a[4] += bf_lo(sv.z); a[5] += bf_hi(sv.z);
            a[6] += bf_lo(sv.w);
        }
#pragma unroll
        for (int q = 0; q < 7; q++) {
            a[q] += __shfl_xor(a[q], 1, 64);
            a[q] += __shfl_xor(a[q], 2, 64);
        }
        if (h == 0) {
            float dn = dinv[n];
            float lg[7];
#pragma unroll
            for (int c = 0; c < 7; c++) lg[c] = dn * a[c] + b2[c];
            float m = lg[0];
#pragma unroll
            for (int c = 1; c < 7; c++) m = fmaxf(m, lg[c]);
            float s = 0.f;
#pragma unroll
            for (int c = 0; c < 7; c++) s += expf(lg[c] - m);
            float ls = m + logf(s);
#pragma unroll
            for (int c = 0; c < 7; c++) out[(size_t)n * 7 + c] = lg[c] - ls;
        }
    }
}

// ---------- launch ----------

extern "C" void kernel_launch(void* const* d_in, const int* in_sizes, int n_in,
                              void* d_out, int out_size, void* d_ws, size_t ws_size,
                              hipStream_t stream) {
    const float* x  = (const float*)d_in[0];
    const int*   ei = (const int*)d_in[1];
    const float* W1 = (const float*)d_in[2];
    const float* b1 = (const float*)d_in[3];
    const float* W2 = (const float*)d_in[4];
    const float* b2 = (const float*)d_in[5];
    float* out = (float*)d_out;

    const int* src = ei;
    const int* dst = ei + N_EDGES;

    char* w = (char*)d_ws;
    int*          btot    = (int*)(w + 0);          //   3128 B
    int*          gbase   = (int*)(w + 4096);       //   3128 B
    float*        dinv    = (float*)(w + 8192);     // 400000 B
    int*          nodeptr = (int*)(w + 408576);     // 400004 B (incl. sentinel)
    int*          hglob   = (int*)(w + 808960);     // 613088 B
    int*          hpre    = (int*)(w + 1422336);    // 613088 B (bucket-local prefixes)
    unsigned int* hs1b    = (unsigned int*)(w + 2036736);  // 3.2 MB (bf16x2)
    unsigned int* hs2b    = (unsigned int*)(w + 5236736);  // 1.6 MB (bf16x2)
    int*          entries = (int*)(w + 6836736);    // 12.8 MB
    unsigned int* wfrag_g = (unsigned int*)(w + 19636736); // 16 KB prepacked W1

    k_hist    <<<NCHUNK + 1, 1024, 0, stream>>>(dst, hglob, W1, wfrag_g);
    k_hpre    <<<NBUK, 256, 0, stream>>>(hglob, hpre, btot);
    k_scan    <<<1, 1024, 0, stream>>>(btot, gbase);
    k_scatter <<<NCHUNK, 1024, 0, stream>>>(src, dst, hpre, gbase, entries);
    k_deg     <<<NBUK, 256, 0, stream>>>(entries, btot, gbase, dinv);
    k_gemm1   <<<1563, 256, 0, stream>>>(x, wfrag_g, dinv, hs1b);
    k_agg1    <<<NBUK, 512, 0, stream>>>(hs1b, entries, btot, gbase, dinv, b1, W2, hs2b, nodeptr);
    k_agg2    <<<NBUK, 512, 0, stream>>>(hs2b, entries, nodeptr, dinv, b2, out);
}